// Round 14
// baseline (78.078 us; speedup 1.0000x reference)
//
#include <hip/hip_runtime.h>

// LBP for semantic dependency parsing — label-difference form, all 3
// iterations fused, u-SPACE chain (u = 2^D), fp16 F payload, per-wave
// double-buffered global_load_lds staging with COUNTED vmcnt.
// This round: 1-ROW-PER-WAVE tiles so that BOTH constraints for
// 2 blocks/CU hold honestly (r13 spilled at 48-VGPR payload + 64-VGPR cap):
//   - staging LDS = 16 waves x 2 slots x 1 row x 3 tensors = 48 KB
//     (block total ~59 KB <= 80 KB -> 2 blocks/CU)
//   - F payload = 8 tiles x 3 tensors x h2v = 24 VGPR (fits 64-VGPR budget)
// Two resident blocks de-bubble the phases: one block's compute-only
// passes 2-3 overlap the other block's HBM streaming (r12/r13 post-mortem:
// 1 block/CU pinned VALUBusy at 34% because memory idled half the time).
//
//   F[b,i,j,k] = 2^(log2e*s) = e^s                (only use of the scores)
//   u_1 = (p1 + F)*r1,          p1 = 2^(-q0[i]), r1 = 1/(1+p1)
//   u_t = (p + F)/(1 + p),      p = u_{t-1} * 2^(-q_{t-1}[i])
//   q_t[k] = q0[k] + mask[k] * sum_i log2(u_s*u_c*u_g)[i,k]
//                               * mask[i]*(i!=j)*(i!=k)
//   out[b,k,j] = 1/(1+2^(-q_3[k]))
//
// Geometry: block (b,j), 1024 thr, 16 waves. Thread = (lane -> k in
// {2*lane, 2*lane+1}, wave wv -> row 16r+wv of tile r). Wave-uniform row
// => wave-coherent live-branch, scalar row-constants, and a reduction with
// no shfl (each (wv,k) partial unique -> direct red[wv][k] write).
// DMA: width-4 global_load_lds (HW-verified size), 2 instrs per row-tensor,
// 6 per tile; counted vmcnt(6) keeps the next tile in flight; the wave
// consumes the row it staged -> NO block barriers in the staging loop.
// Pass 3 recomputes the chain from F (2 rcp/score, r13-verified numerics).

#define TS 128
#define SS (TS * TS)

typedef float    f2v __attribute__((ext_vector_type(2)));
typedef _Float16 h2v __attribute__((ext_vector_type(2)));

constexpr float LOG2E = 1.4426950408889634f;

__device__ __forceinline__ float rcpf(float x)   { return __builtin_amdgcn_rcpf(x); }
__device__ __forceinline__ float clampe(float e) { return fminf(fmaxf(e, -126.0f), 60.0f); }

__device__ __forceinline__ void gload_lds4(const float* g, float* l) {
    __builtin_amdgcn_global_load_lds((const __attribute__((address_space(1))) void*)g,
                                     (__attribute__((address_space(3))) void*)l,
                                     4, 0, 0);
}

// ---- single-block mask format probe: f[0]!=0 byte mask, f[1]!=0 f32, else i32
__global__ void mask_probe(const unsigned char* __restrict__ m, int n, int* __restrict__ f) {
    __shared__ int s1, s23;
    if (threadIdx.x == 0) { s1 = 0; s23 = 0; }
    __syncthreads();
    unsigned a1 = 0, a23 = 0;
    const int n16 = n >> 4;
    const uint4* m4 = (const uint4*)m;
    for (int i = threadIdx.x; i < n16; i += 1024) {
        const uint4 v = m4[i];
        const unsigned o = v.x | v.y | v.z | v.w;
        a1  |= o & 0x0000FF00u;
        a23 |= o & 0xFFFF0000u;
    }
    for (int i = (n16 << 4) + threadIdx.x; i < n; i += 1024) {  // tail bytes
        const unsigned char b = m[i];
        const int r = i & 3;
        if (r == 1) a1 |= b;
        if (r >= 2) a23 |= b;
    }
    if (__any(a1 != 0)  && (threadIdx.x & 63) == 0) atomicOr(&s1, 1);
    if (__any(a23 != 0) && (threadIdx.x & 63) == 0) atomicOr(&s23, 1);
    __syncthreads();
    if (threadIdx.x == 0) { f[0] = s1; f[1] = s23; }
}

__global__ __launch_bounds__(1024, 8)
void lbp_fused(const float* __restrict__ s_edge,
               const float* __restrict__ sib,
               const float* __restrict__ cop,
               const float* __restrict__ grd,
               const void* __restrict__ mask,
               const int* __restrict__ flags,
               float* __restrict__ outp)
{
    __shared__ float ldsS[16][2][TS];    // 16 KB: [wave][slot][k], one row/tile
    __shared__ float ldsC[16][2][TS];
    __shared__ float ldsG[16][2][TS];
    __shared__ float red[16][TS];        // 8 KB: [wave][k]
    __shared__ float q0s[TS], p1s[TS], r1s[TS], g1s[TS], g2s[TS];
    __shared__ unsigned char mrow[TS];

    const int bj = blockIdx.x;
    const int b  = bj >> 7;
    const int j  = bj & (TS - 1);
    const int t  = threadIdx.x;
    const int lane = t & 63;            // k = 2*lane, 2*lane+1
    const int wv = t >> 6;              // wave 0..15; tile r -> row 16r+wv
    const int ka = 2 * lane, kb = 2 * lane + 1;

    // ---- per-column prologue ----
    if (t < TS) {
        const int i = t;
        const int idx = (b * TS + i) * TS + j;
        const float q0 = LOG2E * s_edge[idx];
        q0s[i] = q0;
        const int f1 = flags[0], f23 = flags[1];
        unsigned char mv;
        if (f1)       mv = ((const unsigned char*)mask)[idx] != 0;
        else if (f23) mv = ((const float*)mask)[idx] != 0.0f;
        else          mv = ((const int*)mask)[idx]   != 0;
        mrow[i] = mv;
        const float p1 = exp2f(clampe(-q0));
        p1s[i] = p1;
        r1s[i] = rcpf(1.0f + p1);
    }
    __syncthreads();

    // element base of (b, row, j, 0): b*S^3 + row*S^2 + j*S
    const size_t gcol = (size_t)b * (TS * SS) + (size_t)j * TS;

    // ---- prologue DMA: tile 0 (row wv) into slot 0 ----
    {
        const float* gs = sib + gcol + (size_t)wv * SS + lane;
        const float* gc = cop + gcol + (size_t)wv * SS + lane;
        const float* gg = grd + gcol + (size_t)wv * SS + lane;
        gload_lds4(gs,      &ldsS[wv][0][0]);
        gload_lds4(gs + 64, &ldsS[wv][0][64]);
        gload_lds4(gc,      &ldsC[wv][0][0]);
        gload_lds4(gc + 64, &ldsC[wv][0][64]);
        gload_lds4(gg,      &ldsG[wv][0][0]);
        gload_lds4(gg + 64, &ldsG[wv][0][64]);
    }

    // ---- stage (double-buffered DMA, barrier-free) + pass 1 ----
    h2v Fs[8], Fc[8], Fg[8];
    float a0 = 0.0f, a1 = 0.0f;
    #pragma unroll
    for (int r = 0; r < 8; ++r) {
        if (r < 7) {
            // our ds_reads of the slot we are about to overwrite are done
            asm volatile("s_waitcnt lgkmcnt(0)" ::: "memory");
            const int s = (r + 1) & 1;
            const float* gs = sib + gcol + (size_t)(16 * (r + 1) + wv) * SS + lane;
            const float* gc = cop + gcol + (size_t)(16 * (r + 1) + wv) * SS + lane;
            const float* gg = grd + gcol + (size_t)(16 * (r + 1) + wv) * SS + lane;
            gload_lds4(gs,      &ldsS[wv][s][0]);
            gload_lds4(gs + 64, &ldsS[wv][s][64]);
            gload_lds4(gc,      &ldsC[wv][s][0]);
            gload_lds4(gc + 64, &ldsC[wv][s][64]);
            gload_lds4(gg,      &ldsG[wv][s][0]);
            gload_lds4(gg + 64, &ldsG[wv][s][64]);
            asm volatile("s_waitcnt vmcnt(6)" ::: "memory");   // tile r landed
        } else {
            asm volatile("s_waitcnt vmcnt(0)" ::: "memory");
        }
        const int s0 = r & 1;
        const f2v vs = *(const f2v*)&ldsS[wv][s0][ka];
        const f2v vc = *(const f2v*)&ldsC[wv][s0][ka];
        const f2v vg = *(const f2v*)&ldsG[wv][s0][ka];

        const int i = 16 * r + wv;                 // wave-uniform row
        f2v fs, fc, fg;
        fs[0] = exp2f(LOG2E * vs[0]);  fs[1] = exp2f(LOG2E * vs[1]);
        fc[0] = exp2f(LOG2E * vc[0]);  fc[1] = exp2f(LOG2E * vc[1]);
        fg[0] = exp2f(LOG2E * vg[0]);  fg[1] = exp2f(LOG2E * vg[1]);
        Fs[r] = __builtin_convertvector(fs, h2v);
        Fc[r] = __builtin_convertvector(fc, h2v);
        Fg[r] = __builtin_convertvector(fg, h2v);
        if ((mrow[i] != 0) && (i != j)) {          // wave-coherent branch
            const float p1 = p1s[i], r1 = r1s[i];
            const float l0 = __log2f(((p1 + fs[0]) * r1) * ((p1 + fc[0]) * r1)
                                     * ((p1 + fg[0]) * r1));
            const float l1 = __log2f(((p1 + fs[1]) * r1) * ((p1 + fc[1]) * r1)
                                     * ((p1 + fg[1]) * r1));
            if (i != ka) a0 += l0;
            if (i != kb) a1 += l1;
        }
    }

    // reduce -> q1 -> g1  (each (wv,k) partial unique: direct store)
    { f2v v; v[0] = a0; v[1] = a1; *(f2v*)&red[wv][ka] = v; }
    __syncthreads();
    if (t < TS) {
        float tot = 0.0f;
        #pragma unroll
        for (int w = 0; w < 16; ++w) tot += red[w][t];
        const float q1 = q0s[t] + (mrow[t] ? tot : 0.0f);
        g1s[t] = exp2f(clampe(-q1));
    }
    __syncthreads();

    // ---- pass 2: u2 via 1 rcp/score, pure register math ----
    a0 = 0.0f; a1 = 0.0f;
    #pragma unroll
    for (int r = 0; r < 8; ++r) {
        const int i = 16 * r + wv;
        if ((mrow[i] != 0) && (i != j)) {
            const float p1 = p1s[i], r1 = r1s[i], g1 = g1s[i];
            const f2v fs = __builtin_convertvector(Fs[r], f2v);
            const f2v fc = __builtin_convertvector(Fc[r], f2v);
            const f2v fg = __builtin_convertvector(Fg[r], f2v);
            float l[2];
            #pragma unroll
            for (int c = 0; c < 2; ++c) {
                float p, us, uc, ug;
                us = (p1 + fs[c]) * r1;  p = us * g1;  us = (p + fs[c]) * rcpf(1.0f + p);
                uc = (p1 + fc[c]) * r1;  p = uc * g1;  uc = (p + fc[c]) * rcpf(1.0f + p);
                ug = (p1 + fg[c]) * r1;  p = ug * g1;  ug = (p + fg[c]) * rcpf(1.0f + p);
                l[c] = __log2f(us * uc * ug);
            }
            if (i != ka) a0 += l[0];
            if (i != kb) a1 += l[1];
        }
    }

    // reduce -> q2 -> g2
    { f2v v; v[0] = a0; v[1] = a1; *(f2v*)&red[wv][ka] = v; }
    __syncthreads();
    if (t < TS) {
        float tot = 0.0f;
        #pragma unroll
        for (int w = 0; w < 16; ++w) tot += red[w][t];
        const float q2 = q0s[t] + (mrow[t] ? tot : 0.0f);
        g2s[t] = exp2f(clampe(-q2));
    }
    __syncthreads();

    // ---- pass 3: full chain recompute from F (2 rcp/score) ----
    a0 = 0.0f; a1 = 0.0f;
    #pragma unroll
    for (int r = 0; r < 8; ++r) {
        const int i = 16 * r + wv;
        if ((mrow[i] != 0) && (i != j)) {
            const float p1 = p1s[i], r1 = r1s[i], g1 = g1s[i], g2 = g2s[i];
            const f2v fs = __builtin_convertvector(Fs[r], f2v);
            const f2v fc = __builtin_convertvector(Fc[r], f2v);
            const f2v fg = __builtin_convertvector(Fg[r], f2v);
            float l[2];
            #pragma unroll
            for (int c = 0; c < 2; ++c) {
                float p, us, uc, ug;
                us = (p1 + fs[c]) * r1;  p = us * g1;  us = (p + fs[c]) * rcpf(1.0f + p);
                p = us * g2;  us = (p + fs[c]) * rcpf(1.0f + p);
                uc = (p1 + fc[c]) * r1;  p = uc * g1;  uc = (p + fc[c]) * rcpf(1.0f + p);
                p = uc * g2;  uc = (p + fc[c]) * rcpf(1.0f + p);
                ug = (p1 + fg[c]) * r1;  p = ug * g1;  ug = (p + fg[c]) * rcpf(1.0f + p);
                p = ug * g2;  ug = (p + fg[c]) * rcpf(1.0f + p);
                l[c] = __log2f(us * uc * ug);
            }
            if (i != ka) a0 += l[0];
            if (i != kb) a1 += l[1];
        }
    }

    // reduce -> q3 -> output
    { f2v v; v[0] = a0; v[1] = a1; *(f2v*)&red[wv][ka] = v; }
    __syncthreads();
    if (t < TS) {
        float tot = 0.0f;
        #pragma unroll
        for (int w = 0; w < 16; ++w) tot += red[w][t];
        const float q3 = q0s[t] + (mrow[t] ? tot : 0.0f);
        outp[(b * TS + t) * TS + j] = 1.0f / (1.0f + exp2f(clampe(-q3)));
    }
}

extern "C" void kernel_launch(void* const* d_in, const int* in_sizes, int n_in,
                              void* d_out, int out_size, void* d_ws, size_t ws_size,
                              hipStream_t stream) {
    const float* s_edge = (const float*)d_in[0];
    const float* sib    = (const float*)d_in[1];
    const float* cop    = (const float*)d_in[2];
    const float* grd    = (const float*)d_in[3];
    const void*  mask   = d_in[4];
    float* out = (float*)d_out;

    const int Bn = in_sizes[0] / (TS * TS);   // batch
    const int nMask = in_sizes[4];            // B*S*S elements

    int* flags = (int*)d_ws;

    mask_probe<<<1, 1024, 0, stream>>>((const unsigned char*)mask, nMask, flags);
    lbp_fused<<<Bn * TS, 1024, 0, stream>>>(s_edge, sib, cop, grd, mask, flags, out);
}

// Round 15
// 72.664 us; speedup vs baseline: 1.0745x; 1.0745x over previous
//
#include <hip/hip_runtime.h>

// LBP for semantic dependency parsing — label-difference form, all 3
// iterations fused, u-SPACE chain (u = 2^D), fp16 F payload, direct
// register double-buffered loads (no LDS staging), occupancy pinned at
// 8 waves/EU from BOTH sides.
//
// r14 post-mortem: launch_bounds(1024,8) got 2 blocks/CU resident (occ 80%)
// but the allocator overshot to VGPR=32 and spilled 28 MB of scratch.
// Allocator model from r12-r14: it targets one occupancy tier above the
// declaration, spilling to get there. amdgpu_waves_per_eu(8,8) caps max
// waves at 8/EU so sub-64-VGPR allocation has zero benefit -> no overshoot.
// Dropping LDS-DMA staging (1-row-per-wave needs only 3 dwordx2/tile,
// 6 prefetch regs) removes ~10 VGPRs of addressing pressure + lgkmcnt
// stalls; 32 waves/CU of TLP hide the load latency.
//
//   F[b,i,j,k] = 2^(log2e*s) = e^s                (only use of the scores)
//   u_1 = (p1 + F)*r1,          p1 = 2^(-q0[i]), r1 = 1/(1+p1)
//   u_t = (p + F)/(1 + p),      p = u_{t-1} * 2^(-q_{t-1}[i])
//   q_t[k] = q0[k] + mask[k] * sum_i log2(u_s*u_c*u_g)[i,k]
//                               * mask[i]*(i!=j)*(i!=k)
//   out[b,k,j] = 1/(1+2^(-q_3[k]))
//
// Geometry: block (b,j), 1024 thr, 16 waves. Thread = (lane -> k in
// {2*lane, 2*lane+1}, wave wv -> row 16r+wv of tile r, r=0..7).
// Wave-uniform row => coherent branch, scalar row-constants, direct
// red[wv][k] reduction (no shfl). fp16 F payload = 24 VGPR (precision
// proven r7-r14: absmax 0.0078 vs threshold 0.02). Pass 3 recomputes the
// chain from F (2 rcp/score).

#define TS 128
#define SS (TS * TS)

typedef float    f2v __attribute__((ext_vector_type(2)));
typedef _Float16 h2v __attribute__((ext_vector_type(2)));

constexpr float LOG2E = 1.4426950408889634f;

__device__ __forceinline__ float rcpf(float x)   { return __builtin_amdgcn_rcpf(x); }
__device__ __forceinline__ float clampe(float e) { return fminf(fmaxf(e, -126.0f), 60.0f); }

// ---- single-block mask format probe: f[0]!=0 byte mask, f[1]!=0 f32, else i32
__global__ void mask_probe(const unsigned char* __restrict__ m, int n, int* __restrict__ f) {
    __shared__ int s1, s23;
    if (threadIdx.x == 0) { s1 = 0; s23 = 0; }
    __syncthreads();
    unsigned a1 = 0, a23 = 0;
    const int n16 = n >> 4;
    const uint4* m4 = (const uint4*)m;
    for (int i = threadIdx.x; i < n16; i += 1024) {
        const uint4 v = m4[i];
        const unsigned o = v.x | v.y | v.z | v.w;
        a1  |= o & 0x0000FF00u;
        a23 |= o & 0xFFFF0000u;
    }
    for (int i = (n16 << 4) + threadIdx.x; i < n; i += 1024) {  // tail bytes
        const unsigned char b = m[i];
        const int r = i & 3;
        if (r == 1) a1 |= b;
        if (r >= 2) a23 |= b;
    }
    if (__any(a1 != 0)  && (threadIdx.x & 63) == 0) atomicOr(&s1, 1);
    if (__any(a23 != 0) && (threadIdx.x & 63) == 0) atomicOr(&s23, 1);
    __syncthreads();
    if (threadIdx.x == 0) { f[0] = s1; f[1] = s23; }
}

__global__ __launch_bounds__(1024, 8)
__attribute__((amdgpu_waves_per_eu(8, 8)))
void lbp_fused(const float* __restrict__ s_edge,
               const float* __restrict__ sib,
               const float* __restrict__ cop,
               const float* __restrict__ grd,
               const void* __restrict__ mask,
               const int* __restrict__ flags,
               float* __restrict__ outp)
{
    __shared__ float red[16][TS];        // 8 KB: [wave][k]
    __shared__ float q0s[TS], p1s[TS], r1s[TS], g1s[TS], g2s[TS];
    __shared__ unsigned char mrow[TS];

    const int bj = blockIdx.x;
    const int b  = bj >> 7;
    const int j  = bj & (TS - 1);
    const int t  = threadIdx.x;
    const int lane = t & 63;            // k = 2*lane, 2*lane+1
    const int wv = t >> 6;              // wave 0..15; tile r -> row 16r+wv
    const int ka = 2 * lane, kb = 2 * lane + 1;

    // ---- per-column prologue ----
    if (t < TS) {
        const int i = t;
        const int idx = (b * TS + i) * TS + j;
        const float q0 = LOG2E * s_edge[idx];
        q0s[i] = q0;
        const int f1 = flags[0], f23 = flags[1];
        unsigned char mv;
        if (f1)       mv = ((const unsigned char*)mask)[idx] != 0;
        else if (f23) mv = ((const float*)mask)[idx] != 0.0f;
        else          mv = ((const int*)mask)[idx]   != 0;
        mrow[i] = mv;
        const float p1 = exp2f(clampe(-q0));
        p1s[i] = p1;
        r1s[i] = rcpf(1.0f + p1);
    }
    __syncthreads();

    // per-lane element base of (b, row0=wv, j, 2*lane)
    const size_t gbase = (size_t)b * (TS * SS) + (size_t)j * TS + (size_t)wv * SS + ka;

    // ---- pass 1 with register double-buffered direct loads ----
    h2v Fs[8], Fc[8], Fg[8];
    float a0 = 0.0f, a1 = 0.0f;
    f2v vs = *(const f2v*)(sib + gbase);
    f2v vc = *(const f2v*)(cop + gbase);
    f2v vg = *(const f2v*)(grd + gbase);
    #pragma unroll
    for (int r = 0; r < 8; ++r) {
        f2v nvs, nvc, nvg;
        if (r < 7) {
            const size_t g = gbase + (size_t)(16 * (r + 1)) * SS;
            nvs = *(const f2v*)(sib + g);
            nvc = *(const f2v*)(cop + g);
            nvg = *(const f2v*)(grd + g);
        }
        const int i = 16 * r + wv;                 // wave-uniform row
        f2v fs, fc, fg;
        fs[0] = exp2f(LOG2E * vs[0]);  fs[1] = exp2f(LOG2E * vs[1]);
        fc[0] = exp2f(LOG2E * vc[0]);  fc[1] = exp2f(LOG2E * vc[1]);
        fg[0] = exp2f(LOG2E * vg[0]);  fg[1] = exp2f(LOG2E * vg[1]);
        Fs[r] = __builtin_convertvector(fs, h2v);
        Fc[r] = __builtin_convertvector(fc, h2v);
        Fg[r] = __builtin_convertvector(fg, h2v);
        if ((mrow[i] != 0) && (i != j)) {          // wave-coherent branch
            const float p1 = p1s[i], r1 = r1s[i];
            const float l0 = __log2f(((p1 + fs[0]) * r1) * ((p1 + fc[0]) * r1)
                                     * ((p1 + fg[0]) * r1));
            const float l1 = __log2f(((p1 + fs[1]) * r1) * ((p1 + fc[1]) * r1)
                                     * ((p1 + fg[1]) * r1));
            if (i != ka) a0 += l0;
            if (i != kb) a1 += l1;
        }
        vs = nvs; vc = nvc; vg = nvg;
    }

    // reduce -> q1 -> g1  (each (wv,k) partial unique: direct store)
    { f2v v; v[0] = a0; v[1] = a1; *(f2v*)&red[wv][ka] = v; }
    __syncthreads();
    if (t < TS) {
        float tot = 0.0f;
        #pragma unroll
        for (int w = 0; w < 16; ++w) tot += red[w][t];
        const float q1 = q0s[t] + (mrow[t] ? tot : 0.0f);
        g1s[t] = exp2f(clampe(-q1));
    }
    __syncthreads();

    // ---- pass 2: u2 via 1 rcp/score, pure register math ----
    a0 = 0.0f; a1 = 0.0f;
    #pragma unroll
    for (int r = 0; r < 8; ++r) {
        const int i = 16 * r + wv;
        if ((mrow[i] != 0) && (i != j)) {
            const float p1 = p1s[i], r1 = r1s[i], g1 = g1s[i];
            const f2v fs = __builtin_convertvector(Fs[r], f2v);
            const f2v fc = __builtin_convertvector(Fc[r], f2v);
            const f2v fg = __builtin_convertvector(Fg[r], f2v);
            float l[2];
            #pragma unroll
            for (int c = 0; c < 2; ++c) {
                float p, us, uc, ug;
                us = (p1 + fs[c]) * r1;  p = us * g1;  us = (p + fs[c]) * rcpf(1.0f + p);
                uc = (p1 + fc[c]) * r1;  p = uc * g1;  uc = (p + fc[c]) * rcpf(1.0f + p);
                ug = (p1 + fg[c]) * r1;  p = ug * g1;  ug = (p + fg[c]) * rcpf(1.0f + p);
                l[c] = __log2f(us * uc * ug);
            }
            if (i != ka) a0 += l[0];
            if (i != kb) a1 += l[1];
        }
    }

    // reduce -> q2 -> g2
    { f2v v; v[0] = a0; v[1] = a1; *(f2v*)&red[wv][ka] = v; }
    __syncthreads();
    if (t < TS) {
        float tot = 0.0f;
        #pragma unroll
        for (int w = 0; w < 16; ++w) tot += red[w][t];
        const float q2 = q0s[t] + (mrow[t] ? tot : 0.0f);
        g2s[t] = exp2f(clampe(-q2));
    }
    __syncthreads();

    // ---- pass 3: full chain recompute from F (2 rcp/score) ----
    a0 = 0.0f; a1 = 0.0f;
    #pragma unroll
    for (int r = 0; r < 8; ++r) {
        const int i = 16 * r + wv;
        if ((mrow[i] != 0) && (i != j)) {
            const float p1 = p1s[i], r1 = r1s[i], g1 = g1s[i], g2 = g2s[i];
            const f2v fs = __builtin_convertvector(Fs[r], f2v);
            const f2v fc = __builtin_convertvector(Fc[r], f2v);
            const f2v fg = __builtin_convertvector(Fg[r], f2v);
            float l[2];
            #pragma unroll
            for (int c = 0; c < 2; ++c) {
                float p, us, uc, ug;
                us = (p1 + fs[c]) * r1;  p = us * g1;  us = (p + fs[c]) * rcpf(1.0f + p);
                p = us * g2;  us = (p + fs[c]) * rcpf(1.0f + p);
                uc = (p1 + fc[c]) * r1;  p = uc * g1;  uc = (p + fc[c]) * rcpf(1.0f + p);
                p = uc * g2;  uc = (p + fc[c]) * rcpf(1.0f + p);
                ug = (p1 + fg[c]) * r1;  p = ug * g1;  ug = (p + fg[c]) * rcpf(1.0f + p);
                p = ug * g2;  ug = (p + fg[c]) * rcpf(1.0f + p);
                l[c] = __log2f(us * uc * ug);
            }
            if (i != ka) a0 += l[0];
            if (i != kb) a1 += l[1];
        }
    }

    // reduce -> q3 -> output
    { f2v v; v[0] = a0; v[1] = a1; *(f2v*)&red[wv][ka] = v; }
    __syncthreads();
    if (t < TS) {
        float tot = 0.0f;
        #pragma unroll
        for (int w = 0; w < 16; ++w) tot += red[w][t];
        const float q3 = q0s[t] + (mrow[t] ? tot : 0.0f);
        outp[(b * TS + t) * TS + j] = 1.0f / (1.0f + exp2f(clampe(-q3)));
    }
}

extern "C" void kernel_launch(void* const* d_in, const int* in_sizes, int n_in,
                              void* d_out, int out_size, void* d_ws, size_t ws_size,
                              hipStream_t stream) {
    const float* s_edge = (const float*)d_in[0];
    const float* sib    = (const float*)d_in[1];
    const float* cop    = (const float*)d_in[2];
    const float* grd    = (const float*)d_in[3];
    const void*  mask   = d_in[4];
    float* out = (float*)d_out;

    const int Bn = in_sizes[0] / (TS * TS);   // batch
    const int nMask = in_sizes[4];            // B*S*S elements

    int* flags = (int*)d_ws;

    mask_probe<<<1, 1024, 0, stream>>>((const unsigned char*)mask, nMask, flags);
    lbp_fused<<<Bn * TS, 1024, 0, stream>>>(s_edge, sib, cop, grd, mask, flags, out);
}